// Round 6
// baseline (66.207 us; speedup 1.0000x reference)
//
#include <hip/hip_runtime.h>
#include <math.h>

// Problem constants
#define C_CH   256
#define H_DIM  26
#define W_DIM  26
#define HW     (H_DIM * W_DIM)      // 676
#define N_BOX  128
#define OUTP   3
#define NBIN   (OUTP * OUTP)        // 9
#define FEAT   (C_CH * NBIN)        // 2304
#define H1     1024
#define H2     512

#define K1_GEMV_BLOCKS (H1 / 4)        // 256
#define K1_ROI_BLOCKS  (N_BOX * NBIN)  // 1152
#define K2_BLOCKS      (FEAT / 4)      // 576

#define NEGINF (-INFINITY)

// ---------------------------------------------------------------------------
// Wave-per-row GEMV with float4 loads: dot(M[r,:], v). K % 256 == 0.
// Lane 0 holds the wave-reduced result.
// ---------------------------------------------------------------------------
__device__ __forceinline__ float gemv_row_f4(const float* __restrict__ M,
                                             const float* __restrict__ v,
                                             int r, int K, int lane) {
    const float4* row = (const float4*)(M + (size_t)r * K);
    const float4* vv  = (const float4*)v;
    float s = 0.f;
    for (int k4 = lane; k4 < (K >> 2); k4 += 64) {
        float4 a = row[k4], b = vv[k4];
        s += a.x * b.x + a.y * b.y + a.z * b.z + a.w * b.w;
    }
    #pragma unroll
    for (int off = 32; off; off >>= 1) s += __shfl_down(s, off, 64);
    return s;
}

// ---------------------------------------------------------------------------
// K1: v = W2@W3 (blocks 0..255)
//  || ROI adaptive-max from x DIRECTLY (blocks 256..1407), one block per
//     (box,bin). Lane packing: lane = c_sub*8 + w_sub -> one wave-load covers
//     8 channels x 8 w-columns (32B runs, ~2x line amp, L2-resident x).
//     Writes featsT[r=c*9+bin][n] so K2's reads are coalesced in n.
// ---------------------------------------------------------------------------
__global__ void k1(const float* __restrict__ W2, const float* __restrict__ w3,
                   float* __restrict__ v,
                   const float* __restrict__ x, const int* __restrict__ det,
                   float* __restrict__ featsT) {
    int b = blockIdx.x;
    int tid = threadIdx.x;
    if (b < K1_GEMV_BLOCKS) {
        int r = b * 4 + (tid >> 6);
        int lane = tid & 63;
        float s = gemv_row_f4(W2, w3, r, H2, lane);
        if (lane == 0) v[r] = s;
        return;
    }
    int nbx = b - K1_GEMV_BLOCKS;
    int n = nbx / NBIN, bin = nbx - n * NBIN;
    int bi = bin / OUTP, bj = bin - bi * OUTP;

    int x1 = det[n * 4 + 0], y1 = det[n * 4 + 1];
    int x2 = det[n * 4 + 2], y2 = det[n * 4 + 3];
    int hl = y2 - y1 + 1, wl = x2 - x1 + 1;

    int h0  = y1 + (bi * hl) / OUTP;
    int h1e = y1 + ((bi + 1) * hl + OUTP - 1) / OUTP;   // ceil
    int w0  = x1 + (bj * wl) / OUTP;
    int w1e = x1 + ((bj + 1) * wl + OUTP - 1) / OUTP;
    int hb = h1e - h0, wb = w1e - w0;                    // 1..10 each

    int lane  = tid & 63;
    int wv    = tid >> 6;        // wave id 0..3 -> channel base wv*64
    int c_sub = lane >> 3;       // 0..7
    int w_sub = lane & 7;        // 0..7
    int c0    = wv * 64;

    bool a1 = (w_sub < wb);      // first w pass
    bool a2 = (w_sub + 8 < wb);  // second w pass (wb up to 10)

    float m[8];
    #pragma unroll
    for (int i = 0; i < 8; i++) m[i] = NEGINF;

    for (int h = 0; h < hb; h++) {
        const float* ph = x + (size_t)(h0 + h) * W_DIM + (w0 + w_sub);
        #pragma unroll
        for (int ci = 0; ci < 8; ci++) {     // 8 independent load chains
            const float* pc = ph + (size_t)(c0 + ci * 8 + c_sub) * HW;
            float v1 = a1 ? pc[0] : NEGINF;
            float v2 = a2 ? pc[8] : NEGINF;
            m[ci] = fmaxf(m[ci], fmaxf(v1, v2));
        }
    }
    // combine the 8 w_sub lanes per channel group (lanes are consecutive)
    #pragma unroll
    for (int mask = 1; mask < 8; mask <<= 1) {
        #pragma unroll
        for (int ci = 0; ci < 8; ci++)
            m[ci] = fmaxf(m[ci], __shfl_xor(m[ci], mask, 64));
    }
    if (w_sub == 0) {
        #pragma unroll
        for (int ci = 0; ci < 8; ci++) {
            int c = c0 + ci * 8 + c_sub;
            featsT[(size_t)(c * NBIN + bin) * N_BOX + n] = m[ci];
        }
    }
}

// ---------------------------------------------------------------------------
// K2: each block computes 4 rows of wvec = W1@v, dots them against featsT
//     into partials[block][n] (deterministic). Ticket-counted; the LAST block
//     (no spinning) reduces all partials + collapsed bias + softplus -> out.
// ---------------------------------------------------------------------------
__global__ void k2(const float* __restrict__ W1, const float* __restrict__ v,
                   const float* __restrict__ featsT, float* __restrict__ partials,
                   unsigned int* __restrict__ ticket,
                   const float* __restrict__ b1, const float* __restrict__ b2,
                   const float* __restrict__ w3, const float* __restrict__ b3,
                   float* __restrict__ out) {
    __shared__ float wv_lds[4];
    __shared__ float part2[2][N_BOX];
    __shared__ float red[4];
    __shared__ unsigned int lastflag;

    int b = blockIdx.x, tid = threadIdx.x;
    int lane = tid & 63, wid = tid >> 6;

    // 4 GEMV rows r = b*4 + wid  (r = c*9 + bin feature index)
    int r = b * 4 + wid;
    float s = gemv_row_f4(W1, v, r, H1, lane);
    if (lane == 0) wv_lds[wid] = s;
    __syncthreads();

    // contributions: thread t -> box n = t&127, row-pair pr = t>>7
    int n = tid & 127, pr = tid >> 7;
    float wa = wv_lds[pr * 2 + 0], wb = wv_lds[pr * 2 + 1];
    int r0 = b * 4 + pr * 2;
    float contrib = wa * featsT[(size_t)r0 * N_BOX + n]
                  + wb * featsT[(size_t)(r0 + 1) * N_BOX + n];
    part2[pr][n] = contrib;
    __syncthreads();
    if (tid < N_BOX) partials[(size_t)b * N_BOX + tid] = part2[0][tid] + part2[1][tid];

    // publish: all threads fence (device scope), then one ticket per block
    __threadfence();
    if (tid == 0)
        lastflag = (atomicAdd(ticket, 1u) == (unsigned)(K2_BLOCKS - 1)) ? 1u : 0u;
    __syncthreads();
    if (!lastflag) return;

    // ---- finale: only the LAST-arriving block runs this (all partials done)
    __threadfence();   // acquire side
    float acc = 0.f;
    int nn = tid & 127, half = tid >> 7;           // 2 threads per box
    const int KH = K2_BLOCKS / 2;                  // 288
    for (int k = half * KH; k < half * KH + KH; k++)
        acc += partials[(size_t)k * N_BOX + nn];   // coalesced across nn
    part2[half][nn] = acc;

    // collapsed bias cb = b1.v + b2.w3 + b3
    float sb = 0.f;
    for (int k = tid; k < H1; k += 256) sb += b1[k] * v[k];
    for (int k = tid; k < H2; k += 256) sb += b2[k] * w3[k];
    #pragma unroll
    for (int off = 32; off; off >>= 1) sb += __shfl_down(sb, off, 64);
    if (lane == 0) red[wid] = sb;
    __syncthreads();

    if (tid < N_BOX) {
        float rr = part2[0][tid] + part2[1][tid]
                 + red[0] + red[1] + red[2] + red[3] + b3[0];
        out[tid] = fmaxf(rr, 0.f) + log1pf(expf(-fabsf(rr)));  // stable softplus
    }
}

extern "C" void kernel_launch(void* const* d_in, const int* in_sizes, int n_in,
                              void* d_out, int out_size, void* d_ws, size_t ws_size,
                              hipStream_t stream) {
    const float* x   = (const float*)d_in[0];
    const int*   det = (const int*)  d_in[1];
    const float* W1  = (const float*)d_in[2];
    const float* b1  = (const float*)d_in[3];
    const float* W2  = (const float*)d_in[4];
    const float* b2  = (const float*)d_in[5];
    const float* W3  = (const float*)d_in[6];
    const float* b3  = (const float*)d_in[7];
    float* out = (float*)d_out;

    // workspace layout (floats)
    float* ws       = (float*)d_ws;
    float* v        = ws;                               // 1024
    float* featsT   = v + H1;                           // 2304*128 = 294912
    float* partials = featsT + (size_t)FEAT * N_BOX;    // 576*128 = 73728
    unsigned int* ticket = (unsigned int*)(partials + (size_t)K2_BLOCKS * N_BOX);

    // ticket must be 0 every call (ws is not re-poisoned between replays)
    hipMemsetAsync(ticket, 0, sizeof(unsigned int), stream);

    k1<<<K1_GEMV_BLOCKS + K1_ROI_BLOCKS, 256, 0, stream>>>(W2, W3, v, x, det, featsT);
    k2<<<K2_BLOCKS, 256, 0, stream>>>(W1, v, featsT, partials, ticket,
                                      b1, b2, W3, b3, out);
}

// Round 7
// 58.280 us; speedup vs baseline: 1.1360x; 1.1360x over previous
//
#include <hip/hip_runtime.h>
#include <math.h>

// Problem constants
#define C_CH   256
#define H_DIM  26
#define W_DIM  26
#define HW     (H_DIM * W_DIM)      // 676
#define N_BOX  128
#define OUTP   3
#define NBIN   (OUTP * OUTP)        // 9
#define FEAT   (C_CH * NBIN)        // 2304
#define H1     1024
#define H2     512

// k-slicing of the W1@(W2@w3) chain
#define NJ       16                 // k-slices of width 64 over H1=1024
#define SLICE    64
#define RC       8                  // row-chunks of 288 over FEAT=2304
#define RCH      288
#define NCHAIN   (NJ * RC)          // 128 chain blocks
#define P_STRIDE (FEAT + 1)         // 2305 (last slot = b1.v partial)

#define ROI_BLOCKS (N_BOX * NBIN)   // 1152

#define NEGINF (-INFINITY)

// ---------------------------------------------------------------------------
// Wave-per-row GEMV with float4 loads: dot(M[r,:], v). K % 256 == 0.
// Lane 0 holds the wave-reduced result.
// ---------------------------------------------------------------------------
__device__ __forceinline__ float gemv_row_f4(const float* __restrict__ M,
                                             const float* __restrict__ v,
                                             int r, int K, int lane) {
    const float4* row = (const float4*)(M + (size_t)r * K);
    const float4* vv  = (const float4*)v;
    float s = 0.f;
    for (int k4 = lane; k4 < (K >> 2); k4 += 64) {
        float4 a = row[k4], b = vv[k4];
        s += a.x * b.x + a.y * b.y + a.z * b.z + a.w * b.w;
    }
    #pragma unroll
    for (int off = 32; off; off >>= 1) s += __shfl_down(s, off, 64);
    return s;
}

// ---------------------------------------------------------------------------
// L1: blocks 0..127  : chain block (j = b>>3, rc = b&7)
//       - v_lds[0..63] = W2[j*64+i,:] . w3          (slice of v, local)
//       - p[j][f(r)]  = sum_{k in slice j} W1[r,k] * v[k]  for r in chunk rc
//       - p[j][2304]  = b1[slice j] . v[slice j]     (rc==0 only)
//     blocks 128..1279: ROI adaptive-max, one block per (box,bin),
//       reading x directly (lane = c_sub*8 + w_sub packing), writes
//       feats[n][bin*256 + c].
// ---------------------------------------------------------------------------
__global__ void k1(const float* __restrict__ W2, const float* __restrict__ w3,
                   const float* __restrict__ W1, const float* __restrict__ b1,
                   const float* __restrict__ x, const int* __restrict__ det,
                   float* __restrict__ p, float* __restrict__ feats) {
    int b = blockIdx.x, tid = threadIdx.x;
    int lane = tid & 63, wv = tid >> 6;

    if (b < NCHAIN) {
        __shared__ float v_lds[SLICE];
        int j  = b >> 3;        // k-slice 0..15
        int rc = b & 7;         // row-chunk 0..7

        // ---- v-slice: 64 rows of W2, wave-per-row (16 rows per wave)
        for (int ii = 0; ii < 16; ii++) {
            int i = wv * 16 + ii;
            float s = gemv_row_f4(W2, w3, j * SLICE + i, H2, lane);
            if (lane == 0) v_lds[i] = s;
        }
        __syncthreads();
        float vk = v_lds[lane];             // lane holds v[j*64 + lane]

        // ---- W1 partials: 288 rows, 72 per wave; lane k covers slice col k
        for (int rr = 0; rr < RCH / 4; rr++) {
            int r = rc * RCH + wv * (RCH / 4) + rr;
            float val = W1[(size_t)r * H1 + j * SLICE + lane] * vk;
            #pragma unroll
            for (int off = 32; off; off >>= 1) val += __shfl_down(val, off, 64);
            if (lane == 0) {
                int c = r / NBIN, bin = r - c * NBIN;
                p[(size_t)j * P_STRIDE + bin * C_CH + c] = val;
            }
        }

        // ---- bias partial (once per j)
        if (rc == 0 && wv == 0) {
            float val = b1[j * SLICE + lane] * vk;
            #pragma unroll
            for (int off = 32; off; off >>= 1) val += __shfl_down(val, off, 64);
            if (lane == 0) p[(size_t)j * P_STRIDE + FEAT] = val;
        }
        return;
    }

    // ---------------- ROI pooling (direct x reads) ----------------
    int nbx = b - NCHAIN;
    int n = nbx / NBIN, bin = nbx - n * NBIN;
    int bi = bin / OUTP, bj = bin - bi * OUTP;

    int x1 = det[n * 4 + 0], y1 = det[n * 4 + 1];
    int x2 = det[n * 4 + 2], y2 = det[n * 4 + 3];
    int hl = y2 - y1 + 1, wl = x2 - x1 + 1;

    int h0  = y1 + (bi * hl) / OUTP;
    int h1e = y1 + ((bi + 1) * hl + OUTP - 1) / OUTP;   // ceil
    int w0  = x1 + (bj * wl) / OUTP;
    int w1e = x1 + ((bj + 1) * wl + OUTP - 1) / OUTP;
    int hb = h1e - h0, wb = w1e - w0;                    // 1..10 each

    int c_sub = lane >> 3;       // 0..7
    int w_sub = lane & 7;        // 0..7
    int c0    = wv * 64;

    bool a1 = (w_sub < wb);
    bool a2 = (w_sub + 8 < wb);  // wb up to 10

    float m[8];
    #pragma unroll
    for (int i = 0; i < 8; i++) m[i] = NEGINF;

    for (int h = 0; h < hb; h++) {
        const float* ph = x + (size_t)(h0 + h) * W_DIM + (w0 + w_sub);
        #pragma unroll
        for (int ci = 0; ci < 8; ci++) {     // 8 independent load chains
            const float* pc = ph + (size_t)(c0 + ci * 8 + c_sub) * HW;
            float v1 = a1 ? pc[0] : NEGINF;
            float v2 = a2 ? pc[8] : NEGINF;
            m[ci] = fmaxf(m[ci], fmaxf(v1, v2));
        }
    }
    #pragma unroll
    for (int mask = 1; mask < 8; mask <<= 1) {
        #pragma unroll
        for (int ci = 0; ci < 8; ci++)
            m[ci] = fmaxf(m[ci], __shfl_xor(m[ci], mask, 64));
    }
    if (w_sub == 0) {
        #pragma unroll
        for (int ci = 0; ci < 8; ci++) {
            int c = c0 + ci * 8 + c_sub;
            feats[(size_t)n * FEAT + bin * C_CH + c] = m[ci];
        }
    }
}

// ---------------------------------------------------------------------------
// L2: one block per box. s = sum_f feats[n][f] * (sum_j p[j][f])
//     + sum_j p[j][2304] (b1.v) + b2.w3 + b3  -> softplus.
//     All reduction orders fixed -> deterministic.
// ---------------------------------------------------------------------------
__global__ void kF(const float* __restrict__ p, const float* __restrict__ feats,
                   const float* __restrict__ b2, const float* __restrict__ w3,
                   const float* __restrict__ b3, float* __restrict__ out) {
    int n = blockIdx.x, tid = threadIdx.x;
    const float* fn = feats + (size_t)n * FEAT;

    float s = 0.f;
    #pragma unroll
    for (int i = 0; i < FEAT / 256; i++) {          // 9 features per thread
        int f = i * 256 + tid;
        float wsum = 0.f;
        #pragma unroll
        for (int j = 0; j < NJ; j++) wsum += p[(size_t)j * P_STRIDE + f];
        s += fn[f] * wsum;
    }
    if (tid < NJ) s += p[(size_t)tid * P_STRIDE + FEAT];   // b1.v partials
    #pragma unroll
    for (int k = tid; k < H2; k += 256) s += b2[k] * w3[k];

    #pragma unroll
    for (int off = 32; off; off >>= 1) s += __shfl_down(s, off, 64);
    __shared__ float red[4];
    int lane = tid & 63, wid = tid >> 6;
    if (lane == 0) red[wid] = s;
    __syncthreads();
    if (tid == 0) {
        float r = red[0] + red[1] + red[2] + red[3] + b3[0];
        out[n] = fmaxf(r, 0.f) + log1pf(expf(-fabsf(r)));   // stable softplus
    }
}

extern "C" void kernel_launch(void* const* d_in, const int* in_sizes, int n_in,
                              void* d_out, int out_size, void* d_ws, size_t ws_size,
                              hipStream_t stream) {
    const float* x   = (const float*)d_in[0];
    const int*   det = (const int*)  d_in[1];
    const float* W1  = (const float*)d_in[2];
    const float* b1  = (const float*)d_in[3];
    const float* W2  = (const float*)d_in[4];
    const float* b2  = (const float*)d_in[5];
    const float* W3  = (const float*)d_in[6];
    const float* b3  = (const float*)d_in[7];
    float* out = (float*)d_out;

    // workspace layout (floats)
    float* ws    = (float*)d_ws;
    float* p     = ws;                               // 16*2305 = 36880
    float* feats = p + (size_t)NJ * P_STRIDE;        // 128*2304 = 294912

    k1<<<NCHAIN + ROI_BLOCKS, 256, 0, stream>>>(W2, W3, W1, b1, x, det, p, feats);
    kF<<<N_BOX, 256, 0, stream>>>(p, feats, b2, W3, b3, out);
}

// Round 8
// 24.878 us; speedup vs baseline: 2.6613x; 2.3426x over previous
//
#include <hip/hip_runtime.h>
#include <math.h>

// Problem constants
#define C_CH   256
#define H_DIM  26
#define W_DIM  26
#define HW     (H_DIM * W_DIM)      // 676
#define N_BOX  128
#define OUTP   3
#define NBIN   (OUTP * OUTP)        // 9
#define FEAT   (C_CH * NBIN)        // 2304
#define H1     1024
#define H2     512

#define K1_GEMV_BLOCKS 256              // 4 v-rows each -> 1024
#define ROI_BLOCKS     (N_BOX * NBIN)   // 1152
#define K2_BLOCKS      288              // 8 W1-rows each -> 2304
#define ROWS_PB        8

#define NEGINF (-INFINITY)

// ---------------------------------------------------------------------------
// Wave-per-row GEMV with float4 loads: dot(M[r,:], v). K % 256 == 0.
// Lane 0 holds the wave-reduced result.
// ---------------------------------------------------------------------------
__device__ __forceinline__ float gemv_row_f4(const float* __restrict__ M,
                                             const float* __restrict__ v,
                                             int r, int K, int lane) {
    const float4* row = (const float4*)(M + (size_t)r * K);
    const float4* vv  = (const float4*)v;
    float s = 0.f;
    for (int k4 = lane; k4 < (K >> 2); k4 += 64) {
        float4 a = row[k4], b = vv[k4];
        s += a.x * b.x + a.y * b.y + a.z * b.z + a.w * b.w;
    }
    #pragma unroll
    for (int off = 32; off; off >>= 1) s += __shfl_down(s, off, 64);
    return s;
}

// ---------------------------------------------------------------------------
// K1: blocks 0..255   : v = W2@w3 (4 rows/block); block 0 also zeroes ticket
//     blocks 256..1407: ROI adaptive-max direct from x, one block per
//       (box,bin); lane = c_sub*8 + w_sub packing (proven round 6).
//       Writes featsT[r = c*9+bin][n] (plain stores, flushed at kernel end).
// ---------------------------------------------------------------------------
__global__ void k1(const float* __restrict__ W2, const float* __restrict__ w3,
                   float* __restrict__ v,
                   const float* __restrict__ x, const int* __restrict__ det,
                   float* __restrict__ featsT, unsigned int* __restrict__ ticket) {
    int b = blockIdx.x, tid = threadIdx.x;
    int lane = tid & 63, wv = tid >> 6;

    if (b < K1_GEMV_BLOCKS) {
        if (b == 0 && tid == 0) *ticket = 0u;     // flushed at kernel end
        int r = b * 4 + wv;
        float s = gemv_row_f4(W2, w3, r, H2, lane);
        if (lane == 0) v[r] = s;
        return;
    }

    int nbx = b - K1_GEMV_BLOCKS;
    int n = nbx / NBIN, bin = nbx - n * NBIN;
    int bi = bin / OUTP, bj = bin - bi * OUTP;

    int x1 = det[n * 4 + 0], y1 = det[n * 4 + 1];
    int x2 = det[n * 4 + 2], y2 = det[n * 4 + 3];
    int hl = y2 - y1 + 1, wl = x2 - x1 + 1;

    int h0  = y1 + (bi * hl) / OUTP;
    int h1e = y1 + ((bi + 1) * hl + OUTP - 1) / OUTP;   // ceil
    int w0  = x1 + (bj * wl) / OUTP;
    int w1e = x1 + ((bj + 1) * wl + OUTP - 1) / OUTP;
    int hb = h1e - h0, wb = w1e - w0;                    // 1..10 each

    int c_sub = lane >> 3;       // 0..7
    int w_sub = lane & 7;        // 0..7
    int c0    = wv * 64;

    bool a1 = (w_sub < wb);
    bool a2 = (w_sub + 8 < wb);  // wb up to 10

    float m[8];
    #pragma unroll
    for (int i = 0; i < 8; i++) m[i] = NEGINF;

    for (int h = 0; h < hb; h++) {
        const float* ph = x + (size_t)(h0 + h) * W_DIM + (w0 + w_sub);
        #pragma unroll
        for (int ci = 0; ci < 8; ci++) {     // 8 independent load chains
            const float* pc = ph + (size_t)(c0 + ci * 8 + c_sub) * HW;
            float v1 = a1 ? pc[0] : NEGINF;
            float v2 = a2 ? pc[8] : NEGINF;
            m[ci] = fmaxf(m[ci], fmaxf(v1, v2));
        }
    }
    #pragma unroll
    for (int mask = 1; mask < 8; mask <<= 1) {
        #pragma unroll
        for (int ci = 0; ci < 8; ci++)
            m[ci] = fmaxf(m[ci], __shfl_xor(m[ci], mask, 64));
    }
    if (w_sub == 0) {
        #pragma unroll
        for (int ci = 0; ci < 8; ci++) {
            int c = c0 + ci * 8 + c_sub;
            featsT[(size_t)(c * NBIN + bin) * N_BOX + n] = m[ci];
        }
    }
}

// ---------------------------------------------------------------------------
// K2: 288 blocks x 8 W1-rows. Each block: GEMV its rows, dot vs featsT into
// partials[b][n] via AGENT-scope atomic stores (coherent past XCD L2, no
// fences). Ticket after __syncthreads (compiler drains vmcnt before barrier).
// Last block: collapsed bias + 8-way-ILP partial reduction + softplus -> out.
// Fixed summation order everywhere -> deterministic.
// ---------------------------------------------------------------------------
__global__ void k2(const float* __restrict__ W1, const float* __restrict__ v,
                   const float* __restrict__ featsT, float* __restrict__ partials,
                   unsigned int* __restrict__ ticket,
                   const float* __restrict__ b1, const float* __restrict__ b2,
                   const float* __restrict__ w3, const float* __restrict__ b3,
                   float* __restrict__ out) {
    __shared__ float wv_lds[ROWS_PB];
    __shared__ float part2[2][N_BOX];
    __shared__ float red[4];
    __shared__ unsigned int flag;

    int b = blockIdx.x, tid = threadIdx.x;
    int lane = tid & 63, wid = tid >> 6;
    int r0 = b * ROWS_PB;

    // ---- 8 GEMV rows (2 per wave, unrolled -> 8 f4 loads in flight/lane)
    #pragma unroll
    for (int i = 0; i < 2; i++) {
        int rr = wid * 2 + i;
        float s = gemv_row_f4(W1, v, r0 + rr, H1, lane);
        if (lane == 0) wv_lds[rr] = s;
    }
    __syncthreads();

    // ---- per-box contribution (coalesced featsT reads)
    int half = tid >> 7, n = tid & 127;
    float c = 0.f;
    #pragma unroll
    for (int i = 0; i < 4; i++) {
        int j = half * 4 + i;
        c += wv_lds[j] * featsT[(size_t)(r0 + j) * N_BOX + n];
    }
    part2[half][n] = c;
    __syncthreads();
    if (tid < N_BOX) {
        float val = part2[0][tid] + part2[1][tid];
        __hip_atomic_store(&partials[(size_t)b * N_BOX + tid], val,
                           __ATOMIC_RELAXED, __HIP_MEMORY_SCOPE_AGENT);
    }
    __syncthreads();   // barrier drain: all waves' stores complete here

    if (tid == 0) flag = (atomicAdd(ticket, 1u) == K2_BLOCKS - 1) ? 1u : 0u;
    __syncthreads();
    if (!flag) return;

    // ================= finale (last-arriving block only) =================
    // collapsed bias cb = b1.v + b2.w3 + b3  (plain loads: v flushed at k1 end)
    float sb = 0.f;
    for (int k = tid; k < H1; k += 256) sb += b1[k] * v[k];
    for (int k = tid; k < H2; k += 256) sb += b2[k] * w3[k];
    #pragma unroll
    for (int off = 32; off; off >>= 1) sb += __shfl_down(sb, off, 64);
    if (lane == 0) red[wid] = sb;
    __syncthreads();
    float cb = red[0] + red[1] + red[2] + red[3] + b3[0];

    // partial reduction: (n, half) sums 144 entries, 8 independent chains
    const int KH = K2_BLOCKS / 2;               // 144 = 18*8
    int base = half * KH;
    float a0 = 0.f, a1 = 0.f, a2 = 0.f, a3 = 0.f;
    float a4 = 0.f, a5 = 0.f, a6 = 0.f, a7 = 0.f;
    for (int k = 0; k < KH; k += 8) {
        const float* pp = partials + (size_t)(base + k) * N_BOX + n;
        a0 += __hip_atomic_load(pp + 0 * N_BOX, __ATOMIC_RELAXED, __HIP_MEMORY_SCOPE_AGENT);
        a1 += __hip_atomic_load(pp + 1 * N_BOX, __ATOMIC_RELAXED, __HIP_MEMORY_SCOPE_AGENT);
        a2 += __hip_atomic_load(pp + 2 * N_BOX, __ATOMIC_RELAXED, __HIP_MEMORY_SCOPE_AGENT);
        a3 += __hip_atomic_load(pp + 3 * N_BOX, __ATOMIC_RELAXED, __HIP_MEMORY_SCOPE_AGENT);
        a4 += __hip_atomic_load(pp + 4 * N_BOX, __ATOMIC_RELAXED, __HIP_MEMORY_SCOPE_AGENT);
        a5 += __hip_atomic_load(pp + 5 * N_BOX, __ATOMIC_RELAXED, __HIP_MEMORY_SCOPE_AGENT);
        a6 += __hip_atomic_load(pp + 6 * N_BOX, __ATOMIC_RELAXED, __HIP_MEMORY_SCOPE_AGENT);
        a7 += __hip_atomic_load(pp + 7 * N_BOX, __ATOMIC_RELAXED, __HIP_MEMORY_SCOPE_AGENT);
    }
    float accs = ((a0 + a1) + (a2 + a3)) + ((a4 + a5) + (a6 + a7));
    part2[half][n] = accs;
    __syncthreads();

    if (tid < N_BOX) {
        float r = part2[0][tid] + part2[1][tid] + cb;
        out[tid] = fmaxf(r, 0.f) + log1pf(expf(-fabsf(r)));   // stable softplus
    }
}

extern "C" void kernel_launch(void* const* d_in, const int* in_sizes, int n_in,
                              void* d_out, int out_size, void* d_ws, size_t ws_size,
                              hipStream_t stream) {
    const float* x   = (const float*)d_in[0];
    const int*   det = (const int*)  d_in[1];
    const float* W1  = (const float*)d_in[2];
    const float* b1  = (const float*)d_in[3];
    const float* W2  = (const float*)d_in[4];
    const float* b2  = (const float*)d_in[5];
    const float* W3  = (const float*)d_in[6];
    const float* b3  = (const float*)d_in[7];
    float* out = (float*)d_out;

    // workspace layout (floats)
    float* ws       = (float*)d_ws;
    float* v        = ws;                               // 1024
    float* featsT   = v + H1;                           // 2304*128 = 294912
    float* partials = featsT + (size_t)FEAT * N_BOX;    // 288*128  = 36864
    unsigned int* ticket = (unsigned int*)(partials + (size_t)K2_BLOCKS * N_BOX);

    k1<<<K1_GEMV_BLOCKS + ROI_BLOCKS, 256, 0, stream>>>(W2, W3, v, x, det,
                                                        featsT, ticket);
    k2<<<K2_BLOCKS, 256, 0, stream>>>(W1, v, featsT, partials, ticket,
                                      b1, b2, W3, b3, out);
}

// Round 9
// 24.230 us; speedup vs baseline: 2.7324x; 1.0268x over previous
//
#include <hip/hip_runtime.h>
#include <math.h>

// Problem constants
#define C_CH   256
#define H_DIM  26
#define W_DIM  26
#define HW     (H_DIM * W_DIM)      // 676
#define N_BOX  128
#define OUTP   3
#define NBIN   (OUTP * OUTP)        // 9
#define FEAT   (C_CH * NBIN)        // 2304
#define H1     1024
#define H2     512

// task table: forward DAG, 3 rounds over 705 resident blocks
#define V_TASKS    256                      // v = W2@w3, 4 rows each
#define ROI_TASKS  (N_BOX * NBIN)           // 1152
#define GEMV_TASKS (FEAT / 4)               // 576, 4 W1-rows each
#define T_ROI0     V_TASKS                  // 256
#define T_GEMV0    (T_ROI0 + ROI_TASKS)     // 1408
#define T_BIAS     (T_GEMV0 + GEMV_TASKS)   // 1984
#define T_DOT0     (T_BIAS + 1)             // 1985
#define T_TOTAL    (T_DOT0 + N_BOX)         // 2113
#define NBLOCKS    705                      // <= 1024 co-resident @ (256,4)
#define TOKEN      0x5EED5EEDu
#define SPIN_MAX   1000000

#define NEGINF (-INFINITY)

#define AL(p)    __hip_atomic_load((p),        __ATOMIC_RELAXED, __HIP_MEMORY_SCOPE_AGENT)
#define AS(p, x) __hip_atomic_store((p), (x), __ATOMIC_RELAXED, __HIP_MEMORY_SCOPE_AGENT)

// Wave-per-row GEMV, float4 loads, plain (read-only inputs). Lane 0 has sum.
__device__ __forceinline__ float gemv_row_f4(const float* __restrict__ M,
                                             const float* __restrict__ vv,
                                             int r, int K, int lane) {
    const float4* row = (const float4*)(M + (size_t)r * K);
    const float4* vq  = (const float4*)vv;
    float s = 0.f;
    for (int k4 = lane; k4 < (K >> 2); k4 += 64) {
        float4 a = row[k4], b = vq[k4];
        s += a.x * b.x + a.y * b.y + a.z * b.z + a.w * b.w;
    }
    #pragma unroll
    for (int off = 32; off; off >>= 1) s += __shfl_down(s, off, 64);
    return s;
}

__global__ __launch_bounds__(256, 4)
void fused(const float* __restrict__ W2, const float* __restrict__ w3,
           const float* __restrict__ W1, const float* __restrict__ b1,
           const float* __restrict__ b2, const float* __restrict__ b3,
           const float* __restrict__ x, const int* __restrict__ det,
           float* v, float* wvec, float* cb, float* feats,
           unsigned* vflag, unsigned* roiflag, unsigned* gemvflag,
           unsigned* biasflag, float* __restrict__ out) {
    const int tid = threadIdx.x, lane = tid & 63, wid = tid >> 6;
    __shared__ __align__(16) float sv[H1];   // v staged for gemv tasks
    __shared__ float red[4];

    for (int round = 0; round < 3; ++round) {
        int t = blockIdx.x + round * NBLOCKS;
        if (t >= T_TOTAL) break;

        if (t < V_TASKS) {
            // ---- v rows 4t..4t+3 = W2@w3 ----
            int r = t * 4 + wid;
            float s = gemv_row_f4(W2, w3, r, H2, lane);
            if (lane == 0) AS(&v[r], s);
            __syncthreads();                      // drain stores (vmcnt 0)
            if (tid == 0) AS(&vflag[t], TOKEN);

        } else if (t < T_GEMV0) {
            // ---- ROI adaptive-max for (box,bin), direct from x ----
            int nbx = t - T_ROI0;
            int n = nbx / NBIN, bin = nbx - n * NBIN;
            int bi = bin / OUTP, bj = bin - bi * OUTP;
            int x1 = det[n*4+0], y1 = det[n*4+1];
            int x2 = det[n*4+2], y2 = det[n*4+3];
            int hl = y2 - y1 + 1, wl = x2 - x1 + 1;
            int h0  = y1 + (bi * hl) / OUTP;
            int h1e = y1 + ((bi + 1) * hl + OUTP - 1) / OUTP;
            int w0  = x1 + (bj * wl) / OUTP;
            int w1e = x1 + ((bj + 1) * wl + OUTP - 1) / OUTP;
            int hb = h1e - h0, wb = w1e - w0;     // 1..10 each

            int c_sub = lane >> 3, w_sub = lane & 7, c0 = wid * 64;
            bool a1 = (w_sub < wb), a2 = (w_sub + 8 < wb);

            float m[8];
            #pragma unroll
            for (int i = 0; i < 8; i++) m[i] = NEGINF;
            for (int h = 0; h < hb; h++) {
                const float* ph = x + (size_t)(h0 + h) * W_DIM + (w0 + w_sub);
                #pragma unroll
                for (int ci = 0; ci < 8; ci++) {  // 8 independent load chains
                    const float* pc = ph + (size_t)(c0 + ci * 8 + c_sub) * HW;
                    float v1 = a1 ? pc[0] : NEGINF;
                    float v2 = a2 ? pc[8] : NEGINF;
                    m[ci] = fmaxf(m[ci], fmaxf(v1, v2));
                }
            }
            #pragma unroll
            for (int mask = 1; mask < 8; mask <<= 1) {
                #pragma unroll
                for (int ci = 0; ci < 8; ci++)
                    m[ci] = fmaxf(m[ci], __shfl_xor(m[ci], mask, 64));
            }
            if (w_sub == 0) {
                #pragma unroll
                for (int ci = 0; ci < 8; ci++) {
                    int c = c0 + ci * 8 + c_sub;
                    AS(&feats[(size_t)n * FEAT + bin * C_CH + c], m[ci]);
                }
            }
            __syncthreads();
            if (tid == 0) AS(&roiflag[nbx], TOKEN);

        } else if (t < T_BIAS) {
            // ---- wvec rows 4g..4g+3 = W1@v (bin-major store) ----
            int g = t - T_GEMV0;
            for (int it = 0;; ++it) {             // wait all v flags
                int bad = (AL(&vflag[tid]) != TOKEN) ? 1 : 0;
                if (__syncthreads_count(bad) == 0) break;
                if (it > SPIN_MAX) break;
            }
            for (int i = tid; i < H1; i += 256) sv[i] = AL(&v[i]);
            __syncthreads();

            int r = g * 4 + wid;
            const float4* row = (const float4*)(W1 + (size_t)r * H1);
            const float4* vq  = (const float4*)sv;
            float s = 0.f;
            for (int k4 = lane; k4 < (H1 >> 2); k4 += 64) {
                float4 a = row[k4], b = vq[k4];
                s += a.x * b.x + a.y * b.y + a.z * b.z + a.w * b.w;
            }
            #pragma unroll
            for (int off = 32; off; off >>= 1) s += __shfl_down(s, off, 64);
            if (lane == 0) AS(&wvec[(r % NBIN) * C_CH + (r / NBIN)], s);
            __syncthreads();
            if (tid == 0) AS(&gemvflag[g], TOKEN);

        } else if (t == T_BIAS) {
            // ---- cb = b1.v + b2.w3 + b3 ----
            for (int it = 0;; ++it) {
                int bad = (AL(&vflag[tid]) != TOKEN) ? 1 : 0;
                if (__syncthreads_count(bad) == 0) break;
                if (it > SPIN_MAX) break;
            }
            float s = 0.f;
            for (int k = tid; k < H1; k += 256) s += b1[k] * AL(&v[k]);
            for (int k = tid; k < H2; k += 256) s += b2[k] * w3[k];
            #pragma unroll
            for (int off = 32; off; off >>= 1) s += __shfl_down(s, off, 64);
            if (lane == 0) red[wid] = s;
            __syncthreads();
            if (tid == 0) {
                AS(cb, red[0] + red[1] + red[2] + red[3] + b3[0]);
                AS(biasflag, TOKEN);
            }

        } else {
            // ---- out[n] = softplus(dot(feats[n], wvec) + cb) ----
            int n = t - T_DOT0;
            for (int it = 0;; ++it) {
                int bad = 0;
                if (tid < NBIN && AL(&roiflag[n * NBIN + tid]) != TOKEN) bad = 1;
                if (AL(&gemvflag[tid])       != TOKEN) bad = 1;
                if (AL(&gemvflag[256 + tid]) != TOKEN) bad = 1;
                if (tid < 64 && AL(&gemvflag[512 + tid]) != TOKEN) bad = 1;
                if (tid == 0 && AL(biasflag) != TOKEN) bad = 1;
                if (__syncthreads_count(bad) == 0) break;
                if (it > SPIN_MAX) break;
            }
            float* fn = feats + (size_t)n * FEAT;
            float s = 0.f;
            #pragma unroll
            for (int i = 0; i < NBIN; i++) {
                int f = i * 256 + tid;
                s += AL(&fn[f]) * AL(&wvec[f]);
            }
            #pragma unroll
            for (int off = 32; off; off >>= 1) s += __shfl_down(s, off, 64);
            if (lane == 0) red[wid] = s;
            __syncthreads();
            if (tid == 0) {
                float r = red[0] + red[1] + red[2] + red[3] + AL(cb);
                out[n] = fmaxf(r, 0.f) + log1pf(expf(-fabsf(r)));  // softplus
            }
            __syncthreads();
        }
    }
}

extern "C" void kernel_launch(void* const* d_in, const int* in_sizes, int n_in,
                              void* d_out, int out_size, void* d_ws, size_t ws_size,
                              hipStream_t stream) {
    const float* x   = (const float*)d_in[0];
    const int*   det = (const int*)  d_in[1];
    const float* W1  = (const float*)d_in[2];
    const float* b1  = (const float*)d_in[3];
    const float* W2  = (const float*)d_in[4];
    const float* b2  = (const float*)d_in[5];
    const float* W3  = (const float*)d_in[6];
    const float* b3  = (const float*)d_in[7];
    float* out = (float*)d_out;

    // workspace layout (floats / u32)
    float* ws    = (float*)d_ws;
    float* v     = ws;                               // 1024
    float* wvec  = v + H1;                           // 2304 (bin-major)
    float* cb    = wvec + FEAT;                      // 1
    float* feats = cb + 1;                           // 128*2304 = 294912
    unsigned* vflag    = (unsigned*)(feats + (size_t)N_BOX * FEAT);  // 256
    unsigned* roiflag  = vflag + V_TASKS;            // 1152
    unsigned* gemvflag = roiflag + ROI_TASKS;        // 576
    unsigned* biasflag = gemvflag + GEMV_TASKS;      // 1

    fused<<<NBLOCKS, 256, 0, stream>>>(W2, W3, W1, b1, b2, b3, x, det,
                                       v, wvec, cb, feats,
                                       vflag, roiflag, gemvflag, biasflag, out);
}

// Round 10
// 23.758 us; speedup vs baseline: 2.7868x; 1.0199x over previous
//
#include <hip/hip_runtime.h>
#include <math.h>

// Problem constants
#define C_CH   256
#define H_DIM  26
#define W_DIM  26
#define HW     (H_DIM * W_DIM)      // 676
#define N_BOX  128
#define OUTP   3
#define NBIN   (OUTP * OUTP)        // 9
#define FEAT   (C_CH * NBIN)        // 2304
#define H1     1024
#define H2     512

#define V_BLOCKS   256                  // v = W2@w3, 4 rows each
#define ROI_BLOCKS (N_BOX * NBIN)       // 1152
#define P_BLOCKS   576                  // L2 producers, 4 W1-rows each
#define TOKEN      0x5EED5EEDu
#define SPIN_MAX   200000

#define NEGINF (-INFINITY)
#define AL(p)    __hip_atomic_load((p),        __ATOMIC_RELAXED, __HIP_MEMORY_SCOPE_AGENT)
#define AS(p, x) __hip_atomic_store((p), (x), __ATOMIC_RELAXED, __HIP_MEMORY_SCOPE_AGENT)

// ---------------------------------------------------------------------------
// Wave-per-row GEMV, compile-time K so the f4 loads fully unroll (ILP).
// Lane 0 holds the wave-reduced dot(M[r,:], v).
// ---------------------------------------------------------------------------
template <int K>
__device__ __forceinline__ float gemv_row(const float* __restrict__ M,
                                          const float* __restrict__ v,
                                          int r, int lane) {
    const float4* row = (const float4*)(M + (size_t)r * K);
    const float4* vq  = (const float4*)v;
    float s = 0.f;
    #pragma unroll
    for (int i = 0; i < K / 256; i++) {          // K=1024 -> 4 loads in flight
        int k4 = i * 64 + lane;
        float4 a = row[k4], b = vq[k4];
        s += a.x * b.x + a.y * b.y + a.z * b.z + a.w * b.w;
    }
    #pragma unroll
    for (int off = 32; off; off >>= 1) s += __shfl_down(s, off, 64);
    return s;
}

// ---------------------------------------------------------------------------
// K1: blocks 0..255   : v = W2@w3 (4 rows/block); block 0 also zeroes flags
//     blocks 256..1407: ROI adaptive-max direct from x, one block per
//       (box,bin); lane = c_sub*8 + w_sub packing. featsT[r=c*9+bin][n].
//     All plain stores -- flushed at kernel end (launch-boundary coherence).
// ---------------------------------------------------------------------------
__global__ void k1(const float* __restrict__ W2, const float* __restrict__ w3,
                   float* __restrict__ v,
                   const float* __restrict__ x, const int* __restrict__ det,
                   float* __restrict__ featsT, unsigned* __restrict__ flags) {
    int b = blockIdx.x, tid = threadIdx.x;
    int lane = tid & 63, wid = tid >> 6;

    if (b < V_BLOCKS) {
        if (b == 0)
            for (int f = tid; f < P_BLOCKS; f += 256) flags[f] = 0u;
        int r = b * 4 + wid;
        float s = gemv_row<H2>(W2, w3, r, lane);
        if (lane == 0) v[r] = s;
        return;
    }

    int nbx = b - V_BLOCKS;
    int n = nbx / NBIN, bin = nbx - n * NBIN;
    int bi = bin / OUTP, bj = bin - bi * OUTP;

    int x1 = det[n * 4 + 0], y1 = det[n * 4 + 1];
    int x2 = det[n * 4 + 2], y2 = det[n * 4 + 3];
    int hl = y2 - y1 + 1, wl = x2 - x1 + 1;

    int h0  = y1 + (bi * hl) / OUTP;
    int h1e = y1 + ((bi + 1) * hl + OUTP - 1) / OUTP;   // ceil
    int w0  = x1 + (bj * wl) / OUTP;
    int w1e = x1 + ((bj + 1) * wl + OUTP - 1) / OUTP;
    int hb = h1e - h0, wb = w1e - w0;                    // 1..10 each

    int c_sub = lane >> 3;       // 0..7
    int w_sub = lane & 7;        // 0..7
    int c0    = wid * 64;

    bool a1 = (w_sub < wb);
    bool a2 = (w_sub + 8 < wb);  // wb up to 10

    float m[8];
    #pragma unroll
    for (int i = 0; i < 8; i++) m[i] = NEGINF;

    for (int h = 0; h < hb; h++) {
        const float* ph = x + (size_t)(h0 + h) * W_DIM + (w0 + w_sub);
        #pragma unroll
        for (int ci = 0; ci < 8; ci++) {     // 8 independent load chains
            const float* pc = ph + (size_t)(c0 + ci * 8 + c_sub) * HW;
            float v1 = a1 ? pc[0] : NEGINF;
            float v2 = a2 ? pc[8] : NEGINF;
            m[ci] = fmaxf(m[ci], fmaxf(v1, v2));
        }
    }
    #pragma unroll
    for (int mask = 1; mask < 8; mask <<= 1) {
        #pragma unroll
        for (int ci = 0; ci < 8; ci++)
            m[ci] = fmaxf(m[ci], __shfl_xor(m[ci], mask, 64));
    }
    if (w_sub == 0) {
        #pragma unroll
        for (int ci = 0; ci < 8; ci++) {
            int c = c0 + ci * 8 + c_sub;
            featsT[(size_t)(c * NBIN + bin) * N_BOX + n] = m[ci];
        }
    }
}

// ---------------------------------------------------------------------------
// K2: 577 blocks, all co-resident at __launch_bounds__(256,4).
//   blocks 0..575 (producers): GEMV 4 W1-rows (plain v loads), dot vs featsT,
//     agent-store 128 partials, barrier-drain, agent-store flag[b]=TOKEN.
//   block 576 (consumer): collapsed bias while producers run; read-only
//     flag poll; 8-chain ILP reduction of 288 partials/box; softplus -> out.
// No RMW anywhere. Fixed summation order -> deterministic.
// ---------------------------------------------------------------------------
__global__ __launch_bounds__(256, 4)
void k2(const float* __restrict__ W1, const float* __restrict__ v,
        const float* __restrict__ featsT, float* __restrict__ partials,
        unsigned* __restrict__ flags,
        const float* __restrict__ b1, const float* __restrict__ b2,
        const float* __restrict__ w3, const float* __restrict__ b3,
        float* __restrict__ out) {
    __shared__ float wv_lds[4];
    __shared__ float part2[2][N_BOX];
    __shared__ float red[4];

    int b = blockIdx.x, tid = threadIdx.x;
    int lane = tid & 63, wid = tid >> 6;

    if (b < P_BLOCKS) {
        int r0 = b * 4;
        float s = gemv_row<H1>(W1, v, r0 + wid, lane);
        if (lane == 0) wv_lds[wid] = s;
        __syncthreads();

        int half = tid >> 7, n = tid & 127;
        float c = wv_lds[half * 2 + 0] * featsT[(size_t)(r0 + half * 2 + 0) * N_BOX + n]
                + wv_lds[half * 2 + 1] * featsT[(size_t)(r0 + half * 2 + 1) * N_BOX + n];
        part2[half][n] = c;
        __syncthreads();
        if (tid < N_BOX)
            AS(&partials[(size_t)b * N_BOX + tid], part2[0][tid] + part2[1][tid]);
        __syncthreads();                 // vmcnt(0) drain: stores are in IC
        if (tid == 0) AS(&flags[b], TOKEN);
        return;
    }

    // ---------------- consumer ----------------
    // collapsed bias cb = b1.v + b2.w3 + b3 (plain loads; v flushed by k1)
    float sb = 0.f;
    for (int k = tid; k < H1; k += 256) sb += b1[k] * v[k];
    for (int k = tid; k < H2; k += 256) sb += b2[k] * w3[k];
    #pragma unroll
    for (int off = 32; off; off >>= 1) sb += __shfl_down(sb, off, 64);
    if (lane == 0) red[wid] = sb;
    __syncthreads();
    float cb = red[0] + red[1] + red[2] + red[3] + b3[0];

    // read-only flag poll (each thread owns <=3 flags)
    for (int it = 0;; ++it) {
        int bad = (AL(&flags[tid]) != TOKEN) || (AL(&flags[tid + 256]) != TOKEN);
        if (tid < 64 && AL(&flags[tid + 512]) != TOKEN) bad = 1;
        if (__syncthreads_count(bad) == 0) break;
        if (it > SPIN_MAX) break;        // fail loudly via absmax, never hang
    }

    // reduce 288 partials per (half, box) with 8 independent chains
    int half = tid >> 7, n = tid & 127;
    const int KH = P_BLOCKS / 2;         // 288
    float a0 = 0.f, a1 = 0.f, a2 = 0.f, a3 = 0.f;
    float a4 = 0.f, a5 = 0.f, a6 = 0.f, a7 = 0.f;
    for (int k = 0; k < KH; k += 8) {
        const float* pp = partials + (size_t)(half * KH + k) * N_BOX + n;
        a0 += AL(pp + 0 * N_BOX); a1 += AL(pp + 1 * N_BOX);
        a2 += AL(pp + 2 * N_BOX); a3 += AL(pp + 3 * N_BOX);
        a4 += AL(pp + 4 * N_BOX); a5 += AL(pp + 5 * N_BOX);
        a6 += AL(pp + 6 * N_BOX); a7 += AL(pp + 7 * N_BOX);
    }
    part2[half][n] = ((a0 + a1) + (a2 + a3)) + ((a4 + a5) + (a6 + a7));
    __syncthreads();

    if (tid < N_BOX) {
        float r = part2[0][tid] + part2[1][tid] + cb;
        out[tid] = fmaxf(r, 0.f) + log1pf(expf(-fabsf(r)));   // stable softplus
    }
}

extern "C" void kernel_launch(void* const* d_in, const int* in_sizes, int n_in,
                              void* d_out, int out_size, void* d_ws, size_t ws_size,
                              hipStream_t stream) {
    const float* x   = (const float*)d_in[0];
    const int*   det = (const int*)  d_in[1];
    const float* W1  = (const float*)d_in[2];
    const float* b1  = (const float*)d_in[3];
    const float* W2  = (const float*)d_in[4];
    const float* b2  = (const float*)d_in[5];
    const float* W3  = (const float*)d_in[6];
    const float* b3  = (const float*)d_in[7];
    float* out = (float*)d_out;

    // workspace layout (floats / u32)
    float* ws       = (float*)d_ws;
    float* v        = ws;                               // 1024
    float* featsT   = v + H1;                           // 2304*128 = 294912
    float* partials = featsT + (size_t)FEAT * N_BOX;    // 576*128  = 73728
    unsigned* flags = (unsigned*)(partials + (size_t)P_BLOCKS * N_BOX);  // 576

    k1<<<V_BLOCKS + ROI_BLOCKS, 256, 0, stream>>>(W2, W3, v, x, det, featsT, flags);
    k2<<<P_BLOCKS + 1, 256, 0, stream>>>(W1, v, featsT, partials, flags,
                                         b1, b2, W3, b3, out);
}

// Round 11
// 20.527 us; speedup vs baseline: 3.2253x; 1.1574x over previous
//
#include <hip/hip_runtime.h>
#include <math.h>

// Problem constants
#define C_CH   256
#define H_DIM  26
#define W_DIM  26
#define HW     (H_DIM * W_DIM)      // 676
#define N_BOX  128
#define OUTP   3
#define NBIN   (OUTP * OUTP)        // 9
#define FEAT   (C_CH * NBIN)        // 2304
#define H1     1024
#define H2     512

#define V_BLOCKS   256                  // v = W2@w3, 4 rows each
#define ROI_BLOCKS (N_BOX * NBIN)       // 1152
#define P_BLOCKS   288                  // producers, 8 W1-rows each
#define ROWS_PB    8
#define C_BLOCKS   N_BOX                // 128 consumers, one per box
#define TOKEN      0x5EED5EEDu
#define SPIN_MAX   50000

#define NEGINF (-INFINITY)
#define AL(p)    __hip_atomic_load((p),        __ATOMIC_RELAXED, __HIP_MEMORY_SCOPE_AGENT)
#define AS(p, x) __hip_atomic_store((p), (x), __ATOMIC_RELAXED, __HIP_MEMORY_SCOPE_AGENT)

// ---------------------------------------------------------------------------
// Wave-per-row GEMV, compile-time K -> fully unrolled f4 loads (ILP).
// Lane 0 holds the wave-reduced dot(M[r,:], v).
// ---------------------------------------------------------------------------
template <int K>
__device__ __forceinline__ float gemv_row(const float* __restrict__ M,
                                          const float* __restrict__ v,
                                          int r, int lane) {
    const float4* row = (const float4*)(M + (size_t)r * K);
    const float4* vq  = (const float4*)v;
    float s = 0.f;
    #pragma unroll
    for (int i = 0; i < K / 256; i++) {
        int k4 = i * 64 + lane;
        float4 a = row[k4], b = vq[k4];
        s += a.x * b.x + a.y * b.y + a.z * b.z + a.w * b.w;
    }
    #pragma unroll
    for (int off = 32; off; off >>= 1) s += __shfl_down(s, off, 64);
    return s;
}

// ---------------------------------------------------------------------------
// K1: blocks 0..255   : v = W2@w3 (4 rows/block); block 0 zeroes flags.
//     blocks 256..1407: ROI adaptive-max direct from x, one block per
//       (box,bin); lane = c_sub*8 + w_sub packing. featsT[r=c*9+bin][n].
//     Plain stores; launch boundary makes them coherent for K2.
// ---------------------------------------------------------------------------
__global__ void k1(const float* __restrict__ W2, const float* __restrict__ w3,
                   float* __restrict__ v,
                   const float* __restrict__ x, const int* __restrict__ det,
                   float* __restrict__ featsT, unsigned* __restrict__ flags) {
    int b = blockIdx.x, tid = threadIdx.x;
    int lane = tid & 63, wid = tid >> 6;

    if (b < V_BLOCKS) {
        if (b == 0 && tid < P_BLOCKS) {
            flags[tid] = 0u;
            if (tid < P_BLOCKS - 256) flags[256 + tid] = 0u;
        }
        int r = b * 4 + wid;
        float s = gemv_row<H2>(W2, w3, r, lane);
        if (lane == 0) v[r] = s;
        return;
    }

    int nbx = b - V_BLOCKS;
    int n = nbx / NBIN, bin = nbx - n * NBIN;
    int bi = bin / OUTP, bj = bin - bi * OUTP;

    int x1 = det[n * 4 + 0], y1 = det[n * 4 + 1];
    int x2 = det[n * 4 + 2], y2 = det[n * 4 + 3];
    int hl = y2 - y1 + 1, wl = x2 - x1 + 1;

    int h0  = y1 + (bi * hl) / OUTP;
    int h1e = y1 + ((bi + 1) * hl + OUTP - 1) / OUTP;   // ceil
    int w0  = x1 + (bj * wl) / OUTP;
    int w1e = x1 + ((bj + 1) * wl + OUTP - 1) / OUTP;
    int hb = h1e - h0, wb = w1e - w0;                    // 1..10 each

    int c_sub = lane >> 3;       // 0..7
    int w_sub = lane & 7;        // 0..7
    int c0    = wid * 64;

    bool a1 = (w_sub < wb);
    bool a2 = (w_sub + 8 < wb);  // wb up to 10

    float m[8];
    #pragma unroll
    for (int i = 0; i < 8; i++) m[i] = NEGINF;

    for (int h = 0; h < hb; h++) {
        const float* ph = x + (size_t)(h0 + h) * W_DIM + (w0 + w_sub);
        #pragma unroll
        for (int ci = 0; ci < 8; ci++) {     // 8 independent load chains
            const float* pc = ph + (size_t)(c0 + ci * 8 + c_sub) * HW;
            float v1 = a1 ? pc[0] : NEGINF;
            float v2 = a2 ? pc[8] : NEGINF;
            m[ci] = fmaxf(m[ci], fmaxf(v1, v2));
        }
    }
    #pragma unroll
    for (int mask = 1; mask < 8; mask <<= 1) {
        #pragma unroll
        for (int ci = 0; ci < 8; ci++)
            m[ci] = fmaxf(m[ci], __shfl_xor(m[ci], mask, 64));
    }
    if (w_sub == 0) {
        #pragma unroll
        for (int ci = 0; ci < 8; ci++) {
            int c = c0 + ci * 8 + c_sub;
            featsT[(size_t)(c * NBIN + bin) * N_BOX + n] = m[ci];
        }
    }
}

// ---------------------------------------------------------------------------
// K2: 416 blocks, all co-resident at __launch_bounds__(256,4).
//  blocks 0..287 (producers): 8 W1-rows GEMV (plain v loads), dot vs featsT,
//    agent-store 128 partials + flag[b]. No RMW.
//  blocks 288..415 (consumer for box n): redundant collapsed bias; read-only
//    flag poll (1-2 flags/thread, s_sleep backoff); each thread loads 1-2
//    partials; block reduce; softplus -> out[n]. Fixed order -> deterministic.
// ---------------------------------------------------------------------------
__global__ __launch_bounds__(256, 4)
void k2(const float* __restrict__ W1, const float* __restrict__ v,
        const float* __restrict__ featsT, float* __restrict__ partials,
        unsigned* __restrict__ flags,
        const float* __restrict__ b1, const float* __restrict__ b2,
        const float* __restrict__ w3, const float* __restrict__ b3,
        float* __restrict__ out) {
    __shared__ float wv_lds[ROWS_PB];
    __shared__ float part2[2][N_BOX];
    __shared__ float red[4];
    __shared__ float cbs;

    int b = blockIdx.x, tid = threadIdx.x;
    int lane = tid & 63, wid = tid >> 6;

    if (b < P_BLOCKS) {
        int r0 = b * ROWS_PB;
        float s0 = gemv_row<H1>(W1, v, r0 + wid * 2 + 0, lane);
        float s1 = gemv_row<H1>(W1, v, r0 + wid * 2 + 1, lane);
        if (lane == 0) { wv_lds[wid * 2] = s0; wv_lds[wid * 2 + 1] = s1; }
        __syncthreads();

        int g = tid >> 7, n = tid & 127;     // g in {0,1}: rows 4g..4g+3
        float c = 0.f;
        #pragma unroll
        for (int i = 0; i < 4; i++)
            c += wv_lds[g * 4 + i] * featsT[(size_t)(r0 + g * 4 + i) * N_BOX + n];
        part2[g][n] = c;
        __syncthreads();
        if (tid < N_BOX)
            AS(&partials[(size_t)b * N_BOX + tid], part2[0][tid] + part2[1][tid]);
        __syncthreads();                     // vmcnt(0) drain before flag
        if (tid == 0) AS(&flags[b], TOKEN);
        return;
    }

    // ---------------- consumer for box n ----------------
    int n = b - P_BLOCKS;

    // redundant collapsed bias cb = b1.v + b2.w3 + b3 (plain loads, k1-flushed)
    float sb = 0.f;
    for (int k = tid; k < H1; k += 256) sb += b1[k] * v[k];
    for (int k = tid; k < H2; k += 256) sb += b2[k] * w3[k];
    #pragma unroll
    for (int off = 32; off; off >>= 1) sb += __shfl_down(sb, off, 64);
    if (lane == 0) red[wid] = sb;
    __syncthreads();
    if (tid == 0) cbs = red[0] + red[1] + red[2] + red[3] + b3[0];
    __syncthreads();

    // read-only flag poll: thread t owns flag[t] (+ flag[256+t] for t<32)
    for (int it = 0;; ++it) {
        int bad = (AL(&flags[tid]) != TOKEN) ? 1 : 0;
        if (tid < P_BLOCKS - 256 && AL(&flags[256 + tid]) != TOKEN) bad = 1;
        if (__syncthreads_count(bad) == 0) break;
        if (it > SPIN_MAX) break;            // fail loudly via absmax, no hang
        __builtin_amdgcn_s_sleep(8);
    }

    // each thread: 1-2 partials of column n, then block reduce
    float a = AL(&partials[(size_t)tid * N_BOX + n]);
    if (tid < P_BLOCKS - 256)
        a += AL(&partials[(size_t)(256 + tid) * N_BOX + n]);
    #pragma unroll
    for (int off = 32; off; off >>= 1) a += __shfl_down(a, off, 64);
    if (lane == 0) red[wid] = a;
    __syncthreads();
    if (tid == 0) {
        float r = red[0] + red[1] + red[2] + red[3] + cbs;
        out[n] = fmaxf(r, 0.f) + log1pf(expf(-fabsf(r)));   // stable softplus
    }
}

extern "C" void kernel_launch(void* const* d_in, const int* in_sizes, int n_in,
                              void* d_out, int out_size, void* d_ws, size_t ws_size,
                              hipStream_t stream) {
    const float* x   = (const float*)d_in[0];
    const int*   det = (const int*)  d_in[1];
    const float* W1  = (const float*)d_in[2];
    const float* b1  = (const float*)d_in[3];
    const float* W2  = (const float*)d_in[4];
    const float* b2  = (const float*)d_in[5];
    const float* W3  = (const float*)d_in[6];
    const float* b3  = (const float*)d_in[7];
    float* out = (float*)d_out;

    // workspace layout (floats / u32)
    float* ws       = (float*)d_ws;
    float* v        = ws;                               // 1024
    float* featsT   = v + H1;                           // 2304*128 = 294912
    float* partials = featsT + (size_t)FEAT * N_BOX;    // 288*128  = 36864
    unsigned* flags = (unsigned*)(partials + (size_t)P_BLOCKS * N_BOX);  // 288

    k1<<<V_BLOCKS + ROI_BLOCKS, 256, 0, stream>>>(W2, W3, v, x, det, featsT, flags);
    k2<<<P_BLOCKS + C_BLOCKS, 256, 0, stream>>>(W1, v, featsT, partials, flags,
                                                b1, b2, W3, b3, out);
}